// Round 4
// baseline (27832.858 us; speedup 1.0000x reference)
//
#include <hip/hip_runtime.h>

// DKVMN forward, round 18 — fix the drain-induced scratch spill in kS.
// R17 (3167 µs kS) removed atomics/SMEM from the step loop (5550 -> 3167), but
// counters showed FETCH 2.37 GB / WRITE 7.47 GB per kS dispatch vs 134 MB of
// actual global stores: 56x write amplification = scratch spill. Cause: the
// drain's fully-unrolled 16x ds_read_b128 reduction spikes arch-VGPR demand
// ~70 regs at a point where the file is already split arch=64 + m[16] in acc
// regs -> allocator spills around every drain (1024 thr x 128 subtiles x 512
// blocks). R18: drain is a scalar all-1024-thread reduction — thread
// (j=tid>>8, l=tid&255) sums 16 ds_read_b32 into ONE register, stores one
// fp16. Peak extra pressure ~3 regs; same LDS bytes; conflict-free.
//   kW: wtab[513][512] fp32   kG: etab/atab[1025][256] fp32   (3.2 MB, hot)
//   kS: 512 blocks (b x 2 chunks) x 1024 thr (16 waves x 16 rows x float4);
//       LDS 112 KB: s_w/s_e/s_a 48 KB + s_racc 64 KB; 1 block/CU.
//       Step loop: pure DS+VALU (w broadcast ds_read, plain per-wave partial
//       writes, no atomics, no SMEM).
//   kM: MLP over all 131072 (b,t); sums the 2 fp16 partial regions.
// ws = 3.2 MB + 128 MiB.

#define B_ 256
#define T_ 512
#define N_ 512
#define DK_ 64
#define DV_ 256
#define S_ 64
#define NP_ (B_ * T_)
#define NCID 513
#define NIID 1025
#define TB_ 16

typedef _Float16 h16;
typedef __attribute__((ext_vector_type(4))) _Float16 half4;

__device__ __forceinline__ float dot4(float4 a, float4 b) {
  return a.x * b.x + a.y * b.y + a.z * b.z + a.w * b.w;
}
__device__ __forceinline__ float4 h2f(half4 h) {
  return make_float4((float)h.x, (float)h.y, (float)h.z, (float)h.w);
}
__device__ __forceinline__ half4 f2h(float4 f) {
  half4 h;
  h.x = (h16)f.x; h.y = (h16)f.y; h.z = (h16)f.z; h.w = (h16)f.w;
  return h;
}

// ============ kW: wtab[c][n] = softmax_n(q_c . K_n), 513 blocks ============
__global__ __launch_bounds__(512) void kW(const float* __restrict__ Kmem,
                                          const float* __restrict__ cemb,
                                          float* __restrict__ wtab) {
  __shared__ float s_q[DK_];
  __shared__ float s_red[16];
  const int tid = threadIdx.x, c = blockIdx.x;
  if (tid < DK_) s_q[tid] = c ? cemb[c * DK_ + tid] : 0.f;
  __syncthreads();
  const int n = tid;
  const float4* kr = (const float4*)(Kmem + n * DK_);
  float acc = 0.f;
#pragma unroll
  for (int kk = 0; kk < DK_ / 4; ++kk) acc += dot4(kr[kk], *(const float4*)&s_q[kk * 4]);
  const int lane = tid & 63, wid = tid >> 6;
  float mx = acc;
  for (int off = 32; off; off >>= 1) mx = fmaxf(mx, __shfl_xor(mx, off, 64));
  if (lane == 0) s_red[wid] = mx;
  __syncthreads();
  float gmx = s_red[0];
#pragma unroll
  for (int i = 1; i < 8; ++i) gmx = fmaxf(gmx, s_red[i]);
  const float e = expf(acc - gmx);
  float sum = e;
  for (int off = 32; off; off >>= 1) sum += __shfl_xor(sum, off, 64);
  if (lane == 0) s_red[8 + wid] = sum;
  __syncthreads();
  float gs = 0.f;
#pragma unroll
  for (int i = 0; i < 8; ++i) gs += s_red[8 + i];
  wtab[c * N_ + n] = e / gs;
}

// ============ kG: etab/atab[id][d], 129 blocks x 8 ids =====================
__global__ __launch_bounds__(512) void kG(const float* __restrict__ iemb,
                                          const float* __restrict__ We,
                                          const float* __restrict__ be,
                                          const float* __restrict__ Wa,
                                          const float* __restrict__ ba,
                                          float* __restrict__ etab,
                                          float* __restrict__ atab) {
  __shared__ float s_v[8 * DV_];
  const int tid = threadIdx.x, bi = blockIdx.x;
  {
    const int j = tid >> 6, c4 = tid & 63;
    const int id = bi * 8 + j;
    float4 v = make_float4(0.f, 0.f, 0.f, 0.f);
    if (id >= 1 && id < NIID) v = ((const float4*)iemb)[(size_t)id * 64 + c4];
    *(float4*)&s_v[j * DV_ + c4 * 4] = v;
  }
  __syncthreads();
  const int gate = tid >> 8, d = tid & 255;
  const float4* wr = (const float4*)((gate ? Wa : We) + d * DV_);
  float acc[8];
#pragma unroll
  for (int j = 0; j < 8; ++j) acc[j] = 0.f;
  for (int kk = 0; kk < DV_ / 4; ++kk) {
    const float4 w4 = wr[kk];
#pragma unroll
    for (int j = 0; j < 8; ++j) acc[j] += dot4(w4, *(const float4*)&s_v[j * DV_ + kk * 4]);
  }
  const float bias = gate ? ba[d] : be[d];
#pragma unroll
  for (int j = 0; j < 8; ++j) {
    const int id = bi * 8 + j;
    if (id < NIID) {
      if (gate) atab[(size_t)id * DV_ + d] = tanhf(acc[j] + bias);
      else      etab[(size_t)id * DV_ + d] = 1.f / (1.f + expf(-(acc[j] + bias)));
    }
  }
}

// ============ kS: pure DS+VALU recurrence, 512 blocks x 1024 thr ===========
// block = (b, ch in {0,1}); wave owns 16 rows in registers (m[16] = 64 regs,
// acc-file-backed on gfx950's unified RF).
__global__ __launch_bounds__(1024)
__attribute__((amdgpu_waves_per_eu(4, 4))) void kS(
    const int* __restrict__ concepts, const int* __restrict__ inter,
    const float* __restrict__ Vmem, const float* __restrict__ wtab,
    const float* __restrict__ etab, const float* __restrict__ atab,
    h16* __restrict__ rpart) {
  __shared__ float s_w[TB_][DV_];        // 16 KB: w[t][block's 256-row chunk]
  __shared__ float s_e[TB_][DV_];        // 16 KB
  __shared__ float s_a[TB_][DV_];        // 16 KB
  __shared__ float s_racc[4][16][DV_];   // 64 KB: 4 steps x 16 wave-partials
  const int tid = threadIdx.x, bx = blockIdx.x;
  const int b = bx >> 1, ch = bx & 1;
  const int lane = tid & 63, wv = tid >> 6;  // 16 waves
  const int row0 = ch * 256 + __builtin_amdgcn_readfirstlane(wv * 16);
  float4 m[16];  // rows row0..row0+15, fp32, resident all 512 steps
  {
    const float4* vm4 = (const float4*)Vmem;
#pragma unroll
    for (int i = 0; i < 16; ++i) m[i] = vm4[(size_t)(row0 + i) * 64 + lane];
  }
  const int* cb = concepts + b * T_;
  const int* ib = inter + b * T_;
  const float4* wtab4 = (const float4*)wtab;
  const float4* etab4 = (const float4*)etab;
  const float4* atab4 = (const float4*)atab;
  h16* rp = rpart + (size_t)ch * NP_ * DV_ + (size_t)b * T_ * DV_;

  // cooperative tile staging: w rows for 16 steps (block's 256-col chunk),
  // e/a rows for 16 steps. 3 float4 VMEM loads per thread, L2-resident tables.
  auto stage = [&](int t0) {
    const int tl = tid >> 6, c4 = tid & 63;
    const int cv = cb[t0 + tl];
    const int iv = ib[t0 + tl];
    *(float4*)&s_w[tl][c4 * 4] = wtab4[(size_t)cv * 128 + ch * 64 + c4];
    *(float4*)&s_e[tl][c4 * 4] = etab4[(size_t)iv * 64 + c4];
    *(float4*)&s_a[tl][c4 * 4] = atab4[(size_t)iv * 64 + c4];
  };

  stage(0);
  __syncthreads();

  for (int t0 = 0; t0 < T_; t0 += TB_) {
    for (int s = 0; s < 4; ++s) {  // 4 sub-tiles of 4 steps
#pragma unroll
      for (int j = 0; j < 4; ++j) {
        const int tl = s * 4 + j;
        // wave-uniform broadcast reads: this wave's 16 w values
        const float* wrow = &s_w[tl][wv * 16];
        const float4 wq0 = *(const float4*)(wrow + 0);
        const float4 wq1 = *(const float4*)(wrow + 4);
        const float4 wq2 = *(const float4*)(wrow + 8);
        const float4 wq3 = *(const float4*)(wrow + 12);
        const float4 e4 = *(const float4*)&s_e[tl][lane * 4];
        const float4 a4 = *(const float4*)&s_a[tl][lane * 4];
        float4 racc = make_float4(0.f, 0.f, 0.f, 0.f);
#pragma unroll
        for (int g = 0; g < 4; ++g) {
          const float4 wg = (g == 0) ? wq0 : (g == 1) ? wq1 : (g == 2) ? wq2 : wq3;
#pragma unroll
          for (int i = 0; i < 4; ++i) {
            const int r = g * 4 + i;
            const float w = (i == 0) ? wg.x : (i == 1) ? wg.y : (i == 2) ? wg.z : wg.w;
            racc.x = fmaf(w, m[r].x, racc.x);
            racc.y = fmaf(w, m[r].y, racc.y);
            racc.z = fmaf(w, m[r].z, racc.z);
            racc.w = fmaf(w, m[r].w, racc.w);
            m[r].x = fmaf(-w, fmaf(e4.x, m[r].x, -a4.x), m[r].x);
            m[r].y = fmaf(-w, fmaf(e4.y, m[r].y, -a4.y), m[r].y);
            m[r].z = fmaf(-w, fmaf(e4.z, m[r].z, -a4.z), m[r].z);
            m[r].w = fmaf(-w, fmaf(e4.w, m[r].w, -a4.w), m[r].w);
          }
        }
        // plain per-wave partial write — no atomics
        *(float4*)&s_racc[j][wv][lane * 4] = racc;
      }
      __syncthreads();
      // overlap next-tile staging with the drain (independent LDS regions)
      if (s == 3 && t0 + TB_ < T_) stage(t0 + TB_);
      {
        // drain: ALL 1024 threads, scalar — thread (j,l) sums 16 partials.
        // Peak extra register pressure ~3 (vs ~70 for the unrolled b128
        // version that caused the R17 scratch spill). Consecutive lanes hit
        // consecutive banks (2 lanes/bank = free).
        const int j = tid >> 8, l = tid & 255;
        float acc = 0.f;
#pragma unroll
        for (int w2 = 0; w2 < 16; ++w2) acc += s_racc[j][w2][l];
        rp[(size_t)(t0 + s * 4 + j) * DV_ + l] = (h16)acc;
      }
      __syncthreads();
    }
  }
}

// ============ kM: MLP head, 2048 blocks x 512 thr ==========================
#define MP_ 64
__global__ __launch_bounds__(512) void kM(const int* __restrict__ concepts,
                                          const float* __restrict__ cemb,
                                          const h16* __restrict__ rpart,
                                          const float* __restrict__ W1,
                                          const float* __restrict__ b1,
                                          const float* __restrict__ W2,
                                          const float* __restrict__ b2,
                                          const float* __restrict__ W3,
                                          const float* __restrict__ b3,
                                          float* __restrict__ out) {
  __shared__ float s_f[MP_][DV_ + DK_];  // 80 KB
  __shared__ h16 s_W1[S_][324];          // 40.5 KB (padded)
  __shared__ float s_h1[8][8][S_];       // 16 KB
  __shared__ int s_c[MP_];
  const int tid = threadIdx.x, g = blockIdx.x;
  const int lane = tid & 63, wv = tid >> 6;
  if (tid < MP_) s_c[tid] = concepts[g * MP_ + tid];
  {
    const int j = tid >> 3, f0 = tid & 7;
    const float4* w1r = (const float4*)(W1 + j * 320);
#pragma unroll
    for (int i = 0; i < 10; ++i) {
      const int k4 = f0 + i * 8;
      *(half4*)&s_W1[j][k4 * 4] = f2h(w1r[k4]);
    }
  }
  __syncthreads();
  {
    const half4* p0 = (const half4*)rpart;
    const half4* p1 = p0 + (size_t)NP_ * 64;
#pragma unroll
    for (int i = 0; i < 8; ++i) {
      const int idx = tid + i * 512, p = idx >> 6, c4 = idx & 63;
      const size_t off = (size_t)(g * MP_ + p) * 64 + c4;
      const float4 v0 = h2f(p0[off]);
      const float4 v1 = h2f(p1[off]);
      *(float4*)&s_f[p][c4 * 4] =
          make_float4(v0.x + v1.x, v0.y + v1.y, v0.z + v1.z, v0.w + v1.w);
    }
    const float4* ce4 = (const float4*)cemb;
    const float4 z = make_float4(0.f, 0.f, 0.f, 0.f);
#pragma unroll
    for (int i = 0; i < 2; ++i) {
      const int idx = tid + i * 512, p = idx >> 4, k4 = idx & 15;
      const int c = s_c[p];
      *(float4*)&s_f[p][DV_ + k4 * 4] = c ? ce4[c * 16 + k4] : z;
    }
  }
  __syncthreads();
  const int j = lane;
  float acc[8];
  {
    const float b1j = b1[j];
#pragma unroll
    for (int p = 0; p < 8; ++p) acc[p] = b1j;
  }
  for (int k4 = 0; k4 < 80; ++k4) {
    const float4 w4 = h2f(*(const half4*)&s_W1[j][k4 * 4]);
#pragma unroll
    for (int p = 0; p < 8; ++p)
      acc[p] += dot4(w4, *(const float4*)&s_f[wv * 8 + p][k4 * 4]);
  }
#pragma unroll
  for (int p = 0; p < 8; ++p) s_h1[wv][p][j] = fmaxf(acc[p], 0.f);
  __syncthreads();
  {
    const float b2j = b2[j];
#pragma unroll
    for (int p = 0; p < 8; ++p) acc[p] = b2j;
  }
  const float4* w2r = (const float4*)(W2 + j * S_);
#pragma unroll
  for (int k4 = 0; k4 < S_ / 4; ++k4) {
    const float4 w4 = w2r[k4];
#pragma unroll
    for (int p = 0; p < 8; ++p)
      acc[p] += dot4(w4, *(const float4*)&s_h1[wv][p][k4 * 4]);
  }
  const float w3j = W3[j], b3v = b3[0];
#pragma unroll
  for (int p = 0; p < 8; ++p) {
    float pp = fmaxf(acc[p], 0.f) * w3j;
    for (int off = 32; off; off >>= 1) pp += __shfl_xor(pp, off, 64);
    if (lane == 0)
      out[g * MP_ + wv * 8 + p] = 1.f / (1.f + expf(-(pp + b3v)));
  }
}

extern "C" void kernel_launch(void* const* d_in, const int* in_sizes, int n_in,
                              void* d_out, int out_size, void* d_ws, size_t ws_size,
                              hipStream_t stream) {
  const int* concepts = (const int*)d_in[0];
  const int* interactions = (const int*)d_in[1];
  const float* Kmem = (const float*)d_in[2];
  const float* Vmem = (const float*)d_in[3];
  const float* cemb = (const float*)d_in[4];
  const float* iemb = (const float*)d_in[5];
  const float* We = (const float*)d_in[6];
  const float* be = (const float*)d_in[7];
  const float* Wa = (const float*)d_in[8];
  const float* ba = (const float*)d_in[9];
  const float* W1 = (const float*)d_in[10];
  const float* b1 = (const float*)d_in[11];
  const float* W2 = (const float*)d_in[12];
  const float* b2 = (const float*)d_in[13];
  const float* W3 = (const float*)d_in[14];
  const float* b3 = (const float*)d_in[15];
  float* out = (float*)d_out;

  const size_t sz_w = (size_t)NCID * N_ * 4;
  const size_t sz_e = (size_t)NIID * DV_ * 4;
  float* wtab = (float*)d_ws;
  float* etab = (float*)((char*)d_ws + sz_w);
  float* atab = (float*)((char*)d_ws + sz_w + sz_e);
  h16* rpart = (h16*)((char*)d_ws + sz_w + 2 * sz_e);  // 2 x 64 MiB

  kW<<<dim3(NCID), dim3(512), 0, stream>>>(Kmem, cemb, wtab);
  kG<<<dim3((NIID + 7) / 8), dim3(512), 0, stream>>>(iemb, We, be, Wa, ba, etab, atab);
  kS<<<dim3(B_ * 2), dim3(1024), 0, stream>>>(concepts, interactions, Vmem,
                                              wtab, etab, atab, rpart);
  kM<<<dim3(NP_ / MP_), dim3(512), 0, stream>>>(concepts, cemb, rpart,
                                                W1, b1, W2, b2, W3, b3, out);
}

// Round 5
// 1773.131 us; speedup vs baseline: 15.6970x; 15.6970x over previous
//
#include <hip/hip_runtime.h>

// DKVMN forward, round 19 — cap register-pressure peaks; protect m from scratch.
// R18 post-mortem: reducing DRAIN pressure made spill 8x WORSE (FETCH 41 GB /
// WRITE 57 GB ~= full m[16] scratch round-trip every step; VALUBusy 3%). The
// allocator's placement of m is bistable: the real pressure spike is the
// unrolled 4-step j-loop hoisting 4x6 ds_read_b128 (96 dest regs) above the
// FMA chains; which value spills is allocator whim, and R18's drain edit
// re-ranked the candidates so m lost. R19 caps demand structurally:
//   1) #pragma unroll 1 on the step loop (one step's 24 read-dest regs live);
//   2) m as 16 NAMED float4 variables (no array -> no array-to-scratch path);
//   3) drain = R17's tid<256 float4 form with #pragma unroll 4 (<=4 temps).
// Everything else identical to R17 (measured 3167 us kS).
//   kW: wtab[513][512] fp32   kG: etab/atab[1025][256] fp32   (3.2 MB, hot)
//   kS: 512 blocks (b x 2 chunks) x 1024 thr (16 waves x 16 rows x float4);
//       LDS 112 KB: s_w/s_e/s_a 48 KB + s_racc 64 KB; 1 block/CU.
//       Step loop: pure DS+VALU, no atomics, no SMEM, no unroll.
//   kM: MLP over all 131072 (b,t); sums the 2 fp16 partial regions.
// ws = 3.2 MB + 128 MiB.

#define B_ 256
#define T_ 512
#define N_ 512
#define DK_ 64
#define DV_ 256
#define S_ 64
#define NP_ (B_ * T_)
#define NCID 513
#define NIID 1025
#define TB_ 16

typedef _Float16 h16;
typedef __attribute__((ext_vector_type(4))) _Float16 half4;

__device__ __forceinline__ float dot4(float4 a, float4 b) {
  return a.x * b.x + a.y * b.y + a.z * b.z + a.w * b.w;
}
__device__ __forceinline__ float4 h2f(half4 h) {
  return make_float4((float)h.x, (float)h.y, (float)h.z, (float)h.w);
}
__device__ __forceinline__ half4 f2h(float4 f) {
  half4 h;
  h.x = (h16)f.x; h.y = (h16)f.y; h.z = (h16)f.z; h.w = (h16)f.w;
  return h;
}

// ============ kW: wtab[c][n] = softmax_n(q_c . K_n), 513 blocks ============
__global__ __launch_bounds__(512) void kW(const float* __restrict__ Kmem,
                                          const float* __restrict__ cemb,
                                          float* __restrict__ wtab) {
  __shared__ float s_q[DK_];
  __shared__ float s_red[16];
  const int tid = threadIdx.x, c = blockIdx.x;
  if (tid < DK_) s_q[tid] = c ? cemb[c * DK_ + tid] : 0.f;
  __syncthreads();
  const int n = tid;
  const float4* kr = (const float4*)(Kmem + n * DK_);
  float acc = 0.f;
#pragma unroll
  for (int kk = 0; kk < DK_ / 4; ++kk) acc += dot4(kr[kk], *(const float4*)&s_q[kk * 4]);
  const int lane = tid & 63, wid = tid >> 6;
  float mx = acc;
  for (int off = 32; off; off >>= 1) mx = fmaxf(mx, __shfl_xor(mx, off, 64));
  if (lane == 0) s_red[wid] = mx;
  __syncthreads();
  float gmx = s_red[0];
#pragma unroll
  for (int i = 1; i < 8; ++i) gmx = fmaxf(gmx, s_red[i]);
  const float e = expf(acc - gmx);
  float sum = e;
  for (int off = 32; off; off >>= 1) sum += __shfl_xor(sum, off, 64);
  if (lane == 0) s_red[8 + wid] = sum;
  __syncthreads();
  float gs = 0.f;
#pragma unroll
  for (int i = 0; i < 8; ++i) gs += s_red[8 + i];
  wtab[c * N_ + n] = e / gs;
}

// ============ kG: etab/atab[id][d], 129 blocks x 8 ids =====================
__global__ __launch_bounds__(512) void kG(const float* __restrict__ iemb,
                                          const float* __restrict__ We,
                                          const float* __restrict__ be,
                                          const float* __restrict__ Wa,
                                          const float* __restrict__ ba,
                                          float* __restrict__ etab,
                                          float* __restrict__ atab) {
  __shared__ float s_v[8 * DV_];
  const int tid = threadIdx.x, bi = blockIdx.x;
  {
    const int j = tid >> 6, c4 = tid & 63;
    const int id = bi * 8 + j;
    float4 v = make_float4(0.f, 0.f, 0.f, 0.f);
    if (id >= 1 && id < NIID) v = ((const float4*)iemb)[(size_t)id * 64 + c4];
    *(float4*)&s_v[j * DV_ + c4 * 4] = v;
  }
  __syncthreads();
  const int gate = tid >> 8, d = tid & 255;
  const float4* wr = (const float4*)((gate ? Wa : We) + d * DV_);
  float acc[8];
#pragma unroll
  for (int j = 0; j < 8; ++j) acc[j] = 0.f;
  for (int kk = 0; kk < DV_ / 4; ++kk) {
    const float4 w4 = wr[kk];
#pragma unroll
    for (int j = 0; j < 8; ++j) acc[j] += dot4(w4, *(const float4*)&s_v[j * DV_ + kk * 4]);
  }
  const float bias = gate ? ba[d] : be[d];
#pragma unroll
  for (int j = 0; j < 8; ++j) {
    const int id = bi * 8 + j;
    if (id < NIID) {
      if (gate) atab[(size_t)id * DV_ + d] = tanhf(acc[j] + bias);
      else      etab[(size_t)id * DV_ + d] = 1.f / (1.f + expf(-(acc[j] + bias)));
    }
  }
}

// ============ kS: pure DS+VALU recurrence, 512 blocks x 1024 thr ===========
// block = (b, ch in {0,1}); wave owns 16 rows as NAMED float4 registers.
#define ROWOP(mr, wsel)                                   \
  do {                                                    \
    const float w_ = (wsel);                              \
    racc.x = fmaf(w_, mr.x, racc.x);                      \
    racc.y = fmaf(w_, mr.y, racc.y);                      \
    racc.z = fmaf(w_, mr.z, racc.z);                      \
    racc.w = fmaf(w_, mr.w, racc.w);                      \
    mr.x = fmaf(-w_, fmaf(e4.x, mr.x, -a4.x), mr.x);      \
    mr.y = fmaf(-w_, fmaf(e4.y, mr.y, -a4.y), mr.y);      \
    mr.z = fmaf(-w_, fmaf(e4.z, mr.z, -a4.z), mr.z);      \
    mr.w = fmaf(-w_, fmaf(e4.w, mr.w, -a4.w), mr.w);      \
  } while (0)

__global__ __launch_bounds__(1024)
__attribute__((amdgpu_waves_per_eu(4, 4))) void kS(
    const int* __restrict__ concepts, const int* __restrict__ inter,
    const float* __restrict__ Vmem, const float* __restrict__ wtab,
    const float* __restrict__ etab, const float* __restrict__ atab,
    h16* __restrict__ rpart) {
  __shared__ float s_w[TB_][DV_];        // 16 KB: w[t][block's 256-row chunk]
  __shared__ float s_e[TB_][DV_];        // 16 KB
  __shared__ float s_a[TB_][DV_];        // 16 KB
  __shared__ float s_racc[4][16][DV_];   // 64 KB: 4 steps x 16 wave-partials
  const int tid = threadIdx.x, bx = blockIdx.x;
  const int b = bx >> 1, ch = bx & 1;
  const int lane = tid & 63, wv = tid >> 6;  // 16 waves
  const int row0 = ch * 256 + __builtin_amdgcn_readfirstlane(wv * 16);
  // 16 rows of state, fp32, resident all 512 steps — named regs, no array.
  float4 m0, m1, m2, m3, m4, m5, m6, m7, m8, m9, m10, m11, m12, m13, m14, m15;
  {
    const float4* vm4 = (const float4*)Vmem + (size_t)row0 * 64 + lane;
    m0 = vm4[0 * 64];   m1 = vm4[1 * 64];   m2 = vm4[2 * 64];   m3 = vm4[3 * 64];
    m4 = vm4[4 * 64];   m5 = vm4[5 * 64];   m6 = vm4[6 * 64];   m7 = vm4[7 * 64];
    m8 = vm4[8 * 64];   m9 = vm4[9 * 64];   m10 = vm4[10 * 64]; m11 = vm4[11 * 64];
    m12 = vm4[12 * 64]; m13 = vm4[13 * 64]; m14 = vm4[14 * 64]; m15 = vm4[15 * 64];
  }
  const int* cb = concepts + b * T_;
  const int* ib = inter + b * T_;
  const float4* wtab4 = (const float4*)wtab;
  const float4* etab4 = (const float4*)etab;
  const float4* atab4 = (const float4*)atab;
  h16* rp = rpart + (size_t)ch * NP_ * DV_ + (size_t)b * T_ * DV_;

  // cooperative tile staging: w/e/a rows for 16 steps (3 float4 loads/thread,
  // tables are L2-resident).
  auto stage = [&](int t0) {
    const int tl = tid >> 6, c4 = tid & 63;
    const int cv = cb[t0 + tl];
    const int iv = ib[t0 + tl];
    *(float4*)&s_w[tl][c4 * 4] = wtab4[(size_t)cv * 128 + ch * 64 + c4];
    *(float4*)&s_e[tl][c4 * 4] = etab4[(size_t)iv * 64 + c4];
    *(float4*)&s_a[tl][c4 * 4] = atab4[(size_t)iv * 64 + c4];
  };

  stage(0);
  __syncthreads();

  for (int t0 = 0; t0 < T_; t0 += TB_) {
    for (int s = 0; s < 4; ++s) {  // 4 sub-tiles of 4 steps
#pragma unroll 1                   // CAP PRESSURE: one step's LDS reads live
      for (int j = 0; j < 4; ++j) {
        const int tl = s * 4 + j;
        // wave-uniform broadcast reads: this wave's 16 w values
        const float* wrow = &s_w[tl][wv * 16];
        const float4 wq0 = *(const float4*)(wrow + 0);
        const float4 wq1 = *(const float4*)(wrow + 4);
        const float4 wq2 = *(const float4*)(wrow + 8);
        const float4 wq3 = *(const float4*)(wrow + 12);
        const float4 e4 = *(const float4*)&s_e[tl][lane * 4];
        const float4 a4 = *(const float4*)&s_a[tl][lane * 4];
        float4 racc = make_float4(0.f, 0.f, 0.f, 0.f);
        ROWOP(m0, wq0.x);  ROWOP(m1, wq0.y);  ROWOP(m2, wq0.z);  ROWOP(m3, wq0.w);
        ROWOP(m4, wq1.x);  ROWOP(m5, wq1.y);  ROWOP(m6, wq1.z);  ROWOP(m7, wq1.w);
        ROWOP(m8, wq2.x);  ROWOP(m9, wq2.y);  ROWOP(m10, wq2.z); ROWOP(m11, wq2.w);
        ROWOP(m12, wq3.x); ROWOP(m13, wq3.y); ROWOP(m14, wq3.z); ROWOP(m15, wq3.w);
        // plain per-wave partial write — no atomics
        *(float4*)&s_racc[j][wv][lane * 4] = racc;
      }
      __syncthreads();
      // overlap next-tile staging with the drain (independent LDS regions)
      if (s == 3 && t0 + TB_ < T_) stage(t0 + TB_);
      if (tid < 256) {
        // drain: 4 waves reduce 16 wave-partials; unroll 4 bounds live temps.
        const int j = tid >> 6, l = tid & 63;
        float4 acc = make_float4(0.f, 0.f, 0.f, 0.f);
#pragma unroll 4
        for (int w2 = 0; w2 < 16; ++w2) {
          const float4 v = *(const float4*)&s_racc[j][w2][l * 4];
          acc.x += v.x; acc.y += v.y; acc.z += v.z; acc.w += v.w;
        }
        *(half4*)(rp + (size_t)(t0 + s * 4 + j) * DV_ + l * 4) = f2h(acc);
      }
      __syncthreads();
    }
  }
}

// ============ kM: MLP head, 2048 blocks x 512 thr ==========================
#define MP_ 64
__global__ __launch_bounds__(512) void kM(const int* __restrict__ concepts,
                                          const float* __restrict__ cemb,
                                          const h16* __restrict__ rpart,
                                          const float* __restrict__ W1,
                                          const float* __restrict__ b1,
                                          const float* __restrict__ W2,
                                          const float* __restrict__ b2,
                                          const float* __restrict__ W3,
                                          const float* __restrict__ b3,
                                          float* __restrict__ out) {
  __shared__ float s_f[MP_][DV_ + DK_];  // 80 KB
  __shared__ h16 s_W1[S_][324];          // 40.5 KB (padded)
  __shared__ float s_h1[8][8][S_];       // 16 KB
  __shared__ int s_c[MP_];
  const int tid = threadIdx.x, g = blockIdx.x;
  const int lane = tid & 63, wv = tid >> 6;
  if (tid < MP_) s_c[tid] = concepts[g * MP_ + tid];
  {
    const int j = tid >> 3, f0 = tid & 7;
    const float4* w1r = (const float4*)(W1 + j * 320);
#pragma unroll
    for (int i = 0; i < 10; ++i) {
      const int k4 = f0 + i * 8;
      *(half4*)&s_W1[j][k4 * 4] = f2h(w1r[k4]);
    }
  }
  __syncthreads();
  {
    const half4* p0 = (const half4*)rpart;
    const half4* p1 = p0 + (size_t)NP_ * 64;
#pragma unroll
    for (int i = 0; i < 8; ++i) {
      const int idx = tid + i * 512, p = idx >> 6, c4 = idx & 63;
      const size_t off = (size_t)(g * MP_ + p) * 64 + c4;
      const float4 v0 = h2f(p0[off]);
      const float4 v1 = h2f(p1[off]);
      *(float4*)&s_f[p][c4 * 4] =
          make_float4(v0.x + v1.x, v0.y + v1.y, v0.z + v1.z, v0.w + v1.w);
    }
    const float4* ce4 = (const float4*)cemb;
    const float4 z = make_float4(0.f, 0.f, 0.f, 0.f);
#pragma unroll
    for (int i = 0; i < 2; ++i) {
      const int idx = tid + i * 512, p = idx >> 4, k4 = idx & 15;
      const int c = s_c[p];
      *(float4*)&s_f[p][DV_ + k4 * 4] = c ? ce4[c * 16 + k4] : z;
    }
  }
  __syncthreads();
  const int j = lane;
  float acc[8];
  {
    const float b1j = b1[j];
#pragma unroll
    for (int p = 0; p < 8; ++p) acc[p] = b1j;
  }
  for (int k4 = 0; k4 < 80; ++k4) {
    const float4 w4 = h2f(*(const half4*)&s_W1[j][k4 * 4]);
#pragma unroll
    for (int p = 0; p < 8; ++p)
      acc[p] += dot4(w4, *(const float4*)&s_f[wv * 8 + p][k4 * 4]);
  }
#pragma unroll
  for (int p = 0; p < 8; ++p) s_h1[wv][p][j] = fmaxf(acc[p], 0.f);
  __syncthreads();
  {
    const float b2j = b2[j];
#pragma unroll
    for (int p = 0; p < 8; ++p) acc[p] = b2j;
  }
  const float4* w2r = (const float4*)(W2 + j * S_);
#pragma unroll
  for (int k4 = 0; k4 < S_ / 4; ++k4) {
    const float4 w4 = w2r[k4];
#pragma unroll
    for (int p = 0; p < 8; ++p)
      acc[p] += dot4(w4, *(const float4*)&s_h1[wv][p][k4 * 4]);
  }
  const float w3j = W3[j], b3v = b3[0];
#pragma unroll
  for (int p = 0; p < 8; ++p) {
    float pp = fmaxf(acc[p], 0.f) * w3j;
    for (int off = 32; off; off >>= 1) pp += __shfl_xor(pp, off, 64);
    if (lane == 0)
      out[g * MP_ + wv * 8 + p] = 1.f / (1.f + expf(-(pp + b3v)));
  }
}

extern "C" void kernel_launch(void* const* d_in, const int* in_sizes, int n_in,
                              void* d_out, int out_size, void* d_ws, size_t ws_size,
                              hipStream_t stream) {
  const int* concepts = (const int*)d_in[0];
  const int* interactions = (const int*)d_in[1];
  const float* Kmem = (const float*)d_in[2];
  const float* Vmem = (const float*)d_in[3];
  const float* cemb = (const float*)d_in[4];
  const float* iemb = (const float*)d_in[5];
  const float* We = (const float*)d_in[6];
  const float* be = (const float*)d_in[7];
  const float* Wa = (const float*)d_in[8];
  const float* ba = (const float*)d_in[9];
  const float* W1 = (const float*)d_in[10];
  const float* b1 = (const float*)d_in[11];
  const float* W2 = (const float*)d_in[12];
  const float* b2 = (const float*)d_in[13];
  const float* W3 = (const float*)d_in[14];
  const float* b3 = (const float*)d_in[15];
  float* out = (float*)d_out;

  const size_t sz_w = (size_t)NCID * N_ * 4;
  const size_t sz_e = (size_t)NIID * DV_ * 4;
  float* wtab = (float*)d_ws;
  float* etab = (float*)((char*)d_ws + sz_w);
  float* atab = (float*)((char*)d_ws + sz_w + sz_e);
  h16* rpart = (h16*)((char*)d_ws + sz_w + 2 * sz_e);  // 2 x 64 MiB

  kW<<<dim3(NCID), dim3(512), 0, stream>>>(Kmem, cemb, wtab);
  kG<<<dim3((NIID + 7) / 8), dim3(512), 0, stream>>>(iemb, We, be, Wa, ba, etab, atab);
  kS<<<dim3(B_ * 2), dim3(1024), 0, stream>>>(concepts, interactions, Vmem,
                                              wtab, etab, atab, rpart);
  kM<<<dim3(NP_ / MP_), dim3(512), 0, stream>>>(concepts, cemb, rpart,
                                                W1, b1, W2, b2, W3, b3, out);
}

// Round 6
// 1570.545 us; speedup vs baseline: 17.7218x; 1.1290x over previous
//
#include <hip/hip_runtime.h>

// DKVMN forward, round 20 — softmax-sparsity row skipping in kS.
// R19 post-mortem: spill fixed (WRITE 7.3GB->131MB, VALUBusy 75.7%), kS 1250us
// is now VALU-issue bound (~199 instr/step/wave, floor ~680us). R20 cuts the
// instruction count using the data: logits q.K have sigma=8 (64-dim N(0,1)
// dots), so softmax over 512 rows is extremely peaked — P(w < 1e-7) ~ 0.86
// per row. Rows with w < 1e-7 contribute <2.6e-4 total to r and drift m by
// <1e-4 if their update is skipped — 10x below the 3.9e-3 absmax already
// present from fp16 partials. w is WAVE-UNIFORM per row, so a per-4-row-group
// max + readfirstlane + scalar branch skips all 48 FMAs with zero divergence
// (P(group all-cold) ~ 0.55 -> ~45-55% expected VALU cut).
// R19's staging/drain/named-m/unroll-1 structure (the anti-spill invariant)
// is untouched.
//   kW: wtab[513][512] fp32   kG: etab/atab[1025][256] fp32   (3.2 MB, hot)
//   kS: 512 blocks (b x 2 chunks) x 1024 thr (16 waves x 16 rows x float4);
//       LDS 112 KB; step loop pure DS+VALU with group-skip branches.
//   kM: MLP over all 131072 (b,t); sums the 2 fp16 partial regions.
// ws = 3.2 MB + 128 MiB.

#define B_ 256
#define T_ 512
#define N_ 512
#define DK_ 64
#define DV_ 256
#define S_ 64
#define NP_ (B_ * T_)
#define NCID 513
#define NIID 1025
#define TB_ 16
#define EPSW 1e-7f

typedef _Float16 h16;
typedef __attribute__((ext_vector_type(4))) _Float16 half4;

__device__ __forceinline__ float dot4(float4 a, float4 b) {
  return a.x * b.x + a.y * b.y + a.z * b.z + a.w * b.w;
}
__device__ __forceinline__ float4 h2f(half4 h) {
  return make_float4((float)h.x, (float)h.y, (float)h.z, (float)h.w);
}
__device__ __forceinline__ half4 f2h(float4 f) {
  half4 h;
  h.x = (h16)f.x; h.y = (h16)f.y; h.z = (h16)f.z; h.w = (h16)f.w;
  return h;
}

// ============ kW: wtab[c][n] = softmax_n(q_c . K_n), 513 blocks ============
__global__ __launch_bounds__(512) void kW(const float* __restrict__ Kmem,
                                          const float* __restrict__ cemb,
                                          float* __restrict__ wtab) {
  __shared__ float s_q[DK_];
  __shared__ float s_red[16];
  const int tid = threadIdx.x, c = blockIdx.x;
  if (tid < DK_) s_q[tid] = c ? cemb[c * DK_ + tid] : 0.f;
  __syncthreads();
  const int n = tid;
  const float4* kr = (const float4*)(Kmem + n * DK_);
  float acc = 0.f;
#pragma unroll
  for (int kk = 0; kk < DK_ / 4; ++kk) acc += dot4(kr[kk], *(const float4*)&s_q[kk * 4]);
  const int lane = tid & 63, wid = tid >> 6;
  float mx = acc;
  for (int off = 32; off; off >>= 1) mx = fmaxf(mx, __shfl_xor(mx, off, 64));
  if (lane == 0) s_red[wid] = mx;
  __syncthreads();
  float gmx = s_red[0];
#pragma unroll
  for (int i = 1; i < 8; ++i) gmx = fmaxf(gmx, s_red[i]);
  const float e = expf(acc - gmx);
  float sum = e;
  for (int off = 32; off; off >>= 1) sum += __shfl_xor(sum, off, 64);
  if (lane == 0) s_red[8 + wid] = sum;
  __syncthreads();
  float gs = 0.f;
#pragma unroll
  for (int i = 0; i < 8; ++i) gs += s_red[8 + i];
  wtab[c * N_ + n] = e / gs;
}

// ============ kG: etab/atab[id][d], 129 blocks x 8 ids =====================
__global__ __launch_bounds__(512) void kG(const float* __restrict__ iemb,
                                          const float* __restrict__ We,
                                          const float* __restrict__ be,
                                          const float* __restrict__ Wa,
                                          const float* __restrict__ ba,
                                          float* __restrict__ etab,
                                          float* __restrict__ atab) {
  __shared__ float s_v[8 * DV_];
  const int tid = threadIdx.x, bi = blockIdx.x;
  {
    const int j = tid >> 6, c4 = tid & 63;
    const int id = bi * 8 + j;
    float4 v = make_float4(0.f, 0.f, 0.f, 0.f);
    if (id >= 1 && id < NIID) v = ((const float4*)iemb)[(size_t)id * 64 + c4];
    *(float4*)&s_v[j * DV_ + c4 * 4] = v;
  }
  __syncthreads();
  const int gate = tid >> 8, d = tid & 255;
  const float4* wr = (const float4*)((gate ? Wa : We) + d * DV_);
  float acc[8];
#pragma unroll
  for (int j = 0; j < 8; ++j) acc[j] = 0.f;
  for (int kk = 0; kk < DV_ / 4; ++kk) {
    const float4 w4 = wr[kk];
#pragma unroll
    for (int j = 0; j < 8; ++j) acc[j] += dot4(w4, *(const float4*)&s_v[j * DV_ + kk * 4]);
  }
  const float bias = gate ? ba[d] : be[d];
#pragma unroll
  for (int j = 0; j < 8; ++j) {
    const int id = bi * 8 + j;
    if (id < NIID) {
      if (gate) atab[(size_t)id * DV_ + d] = tanhf(acc[j] + bias);
      else      etab[(size_t)id * DV_ + d] = 1.f / (1.f + expf(-(acc[j] + bias)));
    }
  }
}

// ============ kS: sparse DS+VALU recurrence, 512 blocks x 1024 thr =========
// block = (b, ch in {0,1}); wave owns 16 rows as NAMED float4 registers.
#define ROWOP(mr, wsel)                                   \
  do {                                                    \
    const float w_ = (wsel);                              \
    racc.x = fmaf(w_, mr.x, racc.x);                      \
    racc.y = fmaf(w_, mr.y, racc.y);                      \
    racc.z = fmaf(w_, mr.z, racc.z);                      \
    racc.w = fmaf(w_, mr.w, racc.w);                      \
    mr.x = fmaf(-w_, fmaf(e4.x, mr.x, -a4.x), mr.x);      \
    mr.y = fmaf(-w_, fmaf(e4.y, mr.y, -a4.y), mr.y);      \
    mr.z = fmaf(-w_, fmaf(e4.z, mr.z, -a4.z), mr.z);      \
    mr.w = fmaf(-w_, fmaf(e4.w, mr.w, -a4.w), mr.w);      \
  } while (0)

// 4-row group, skipped entirely when all 4 softmax weights < EPSW.
// w is lane-uniform -> readfirstlane makes the branch SCALAR (no divergence).
#define GRP4(wq, A, B, C, D)                                              \
  do {                                                                    \
    const float gmx_ = fmaxf(fmaxf(wq.x, wq.y), fmaxf(wq.z, wq.w));       \
    if (__int_as_float(__builtin_amdgcn_readfirstlane(                    \
            __float_as_int(gmx_))) > EPSW) {                              \
      ROWOP(A, wq.x); ROWOP(B, wq.y); ROWOP(C, wq.z); ROWOP(D, wq.w);     \
    }                                                                     \
  } while (0)

__global__ __launch_bounds__(1024)
__attribute__((amdgpu_waves_per_eu(4, 4))) void kS(
    const int* __restrict__ concepts, const int* __restrict__ inter,
    const float* __restrict__ Vmem, const float* __restrict__ wtab,
    const float* __restrict__ etab, const float* __restrict__ atab,
    h16* __restrict__ rpart) {
  __shared__ float s_w[TB_][DV_];        // 16 KB: w[t][block's 256-row chunk]
  __shared__ float s_e[TB_][DV_];        // 16 KB
  __shared__ float s_a[TB_][DV_];        // 16 KB
  __shared__ float s_racc[4][16][DV_];   // 64 KB: 4 steps x 16 wave-partials
  const int tid = threadIdx.x, bx = blockIdx.x;
  const int b = bx >> 1, ch = bx & 1;
  const int lane = tid & 63, wv = tid >> 6;  // 16 waves
  const int row0 = ch * 256 + __builtin_amdgcn_readfirstlane(wv * 16);
  // 16 rows of state, fp32, resident all 512 steps — named regs, no array.
  float4 m0, m1, m2, m3, m4, m5, m6, m7, m8, m9, m10, m11, m12, m13, m14, m15;
  {
    const float4* vm4 = (const float4*)Vmem + (size_t)row0 * 64 + lane;
    m0 = vm4[0 * 64];   m1 = vm4[1 * 64];   m2 = vm4[2 * 64];   m3 = vm4[3 * 64];
    m4 = vm4[4 * 64];   m5 = vm4[5 * 64];   m6 = vm4[6 * 64];   m7 = vm4[7 * 64];
    m8 = vm4[8 * 64];   m9 = vm4[9 * 64];   m10 = vm4[10 * 64]; m11 = vm4[11 * 64];
    m12 = vm4[12 * 64]; m13 = vm4[13 * 64]; m14 = vm4[14 * 64]; m15 = vm4[15 * 64];
  }
  const int* cb = concepts + b * T_;
  const int* ib = inter + b * T_;
  const float4* wtab4 = (const float4*)wtab;
  const float4* etab4 = (const float4*)etab;
  const float4* atab4 = (const float4*)atab;
  h16* rp = rpart + (size_t)ch * NP_ * DV_ + (size_t)b * T_ * DV_;

  // cooperative tile staging: w/e/a rows for 16 steps (3 float4 loads/thread,
  // tables are L2-resident).
  auto stage = [&](int t0) {
    const int tl = tid >> 6, c4 = tid & 63;
    const int cv = cb[t0 + tl];
    const int iv = ib[t0 + tl];
    *(float4*)&s_w[tl][c4 * 4] = wtab4[(size_t)cv * 128 + ch * 64 + c4];
    *(float4*)&s_e[tl][c4 * 4] = etab4[(size_t)iv * 64 + c4];
    *(float4*)&s_a[tl][c4 * 4] = atab4[(size_t)iv * 64 + c4];
  };

  stage(0);
  __syncthreads();

  for (int t0 = 0; t0 < T_; t0 += TB_) {
    for (int s = 0; s < 4; ++s) {  // 4 sub-tiles of 4 steps
#pragma unroll 1                   // CAP PRESSURE: one step's LDS reads live
      for (int j = 0; j < 4; ++j) {
        const int tl = s * 4 + j;
        // wave-uniform broadcast reads: this wave's 16 w values
        const float* wrow = &s_w[tl][wv * 16];
        const float4 wq0 = *(const float4*)(wrow + 0);
        const float4 wq1 = *(const float4*)(wrow + 4);
        const float4 wq2 = *(const float4*)(wrow + 8);
        const float4 wq3 = *(const float4*)(wrow + 12);
        const float4 e4 = *(const float4*)&s_e[tl][lane * 4];
        const float4 a4 = *(const float4*)&s_a[tl][lane * 4];
        float4 racc = make_float4(0.f, 0.f, 0.f, 0.f);
        GRP4(wq0, m0, m1, m2, m3);
        GRP4(wq1, m4, m5, m6, m7);
        GRP4(wq2, m8, m9, m10, m11);
        GRP4(wq3, m12, m13, m14, m15);
        // plain per-wave partial write — no atomics
        *(float4*)&s_racc[j][wv][lane * 4] = racc;
      }
      __syncthreads();
      // overlap next-tile staging with the drain (independent LDS regions)
      if (s == 3 && t0 + TB_ < T_) stage(t0 + TB_);
      if (tid < 256) {
        // drain: 4 waves reduce 16 wave-partials; unroll 4 bounds live temps.
        const int j = tid >> 6, l = tid & 63;
        float4 acc = make_float4(0.f, 0.f, 0.f, 0.f);
#pragma unroll 4
        for (int w2 = 0; w2 < 16; ++w2) {
          const float4 v = *(const float4*)&s_racc[j][w2][l * 4];
          acc.x += v.x; acc.y += v.y; acc.z += v.z; acc.w += v.w;
        }
        *(half4*)(rp + (size_t)(t0 + s * 4 + j) * DV_ + l * 4) = f2h(acc);
      }
      __syncthreads();
    }
  }
}

// ============ kM: MLP head, 2048 blocks x 512 thr ==========================
#define MP_ 64
__global__ __launch_bounds__(512) void kM(const int* __restrict__ concepts,
                                          const float* __restrict__ cemb,
                                          const h16* __restrict__ rpart,
                                          const float* __restrict__ W1,
                                          const float* __restrict__ b1,
                                          const float* __restrict__ W2,
                                          const float* __restrict__ b2,
                                          const float* __restrict__ W3,
                                          const float* __restrict__ b3,
                                          float* __restrict__ out) {
  __shared__ float s_f[MP_][DV_ + DK_];  // 80 KB
  __shared__ h16 s_W1[S_][324];          // 40.5 KB (padded)
  __shared__ float s_h1[8][8][S_];       // 16 KB
  __shared__ int s_c[MP_];
  const int tid = threadIdx.x, g = blockIdx.x;
  const int lane = tid & 63, wv = tid >> 6;
  if (tid < MP_) s_c[tid] = concepts[g * MP_ + tid];
  {
    const int j = tid >> 3, f0 = tid & 7;
    const float4* w1r = (const float4*)(W1 + j * 320);
#pragma unroll
    for (int i = 0; i < 10; ++i) {
      const int k4 = f0 + i * 8;
      *(half4*)&s_W1[j][k4 * 4] = f2h(w1r[k4]);
    }
  }
  __syncthreads();
  {
    const half4* p0 = (const half4*)rpart;
    const half4* p1 = p0 + (size_t)NP_ * 64;
#pragma unroll
    for (int i = 0; i < 8; ++i) {
      const int idx = tid + i * 512, p = idx >> 6, c4 = idx & 63;
      const size_t off = (size_t)(g * MP_ + p) * 64 + c4;
      const float4 v0 = h2f(p0[off]);
      const float4 v1 = h2f(p1[off]);
      *(float4*)&s_f[p][c4 * 4] =
          make_float4(v0.x + v1.x, v0.y + v1.y, v0.z + v1.z, v0.w + v1.w);
    }
    const float4* ce4 = (const float4*)cemb;
    const float4 z = make_float4(0.f, 0.f, 0.f, 0.f);
#pragma unroll
    for (int i = 0; i < 2; ++i) {
      const int idx = tid + i * 512, p = idx >> 4, k4 = idx & 15;
      const int c = s_c[p];
      *(float4*)&s_f[p][DV_ + k4 * 4] = c ? ce4[c * 16 + k4] : z;
    }
  }
  __syncthreads();
  const int j = lane;
  float acc[8];
  {
    const float b1j = b1[j];
#pragma unroll
    for (int p = 0; p < 8; ++p) acc[p] = b1j;
  }
  for (int k4 = 0; k4 < 80; ++k4) {
    const float4 w4 = h2f(*(const half4*)&s_W1[j][k4 * 4]);
#pragma unroll
    for (int p = 0; p < 8; ++p)
      acc[p] += dot4(w4, *(const float4*)&s_f[wv * 8 + p][k4 * 4]);
  }
#pragma unroll
  for (int p = 0; p < 8; ++p) s_h1[wv][p][j] = fmaxf(acc[p], 0.f);
  __syncthreads();
  {
    const float b2j = b2[j];
#pragma unroll
    for (int p = 0; p < 8; ++p) acc[p] = b2j;
  }
  const float4* w2r = (const float4*)(W2 + j * S_);
#pragma unroll
  for (int k4 = 0; k4 < S_ / 4; ++k4) {
    const float4 w4 = w2r[k4];
#pragma unroll
    for (int p = 0; p < 8; ++p)
      acc[p] += dot4(w4, *(const float4*)&s_h1[wv][p][k4 * 4]);
  }
  const float w3j = W3[j], b3v = b3[0];
#pragma unroll
  for (int p = 0; p < 8; ++p) {
    float pp = fmaxf(acc[p], 0.f) * w3j;
    for (int off = 32; off; off >>= 1) pp += __shfl_xor(pp, off, 64);
    if (lane == 0)
      out[g * MP_ + wv * 8 + p] = 1.f / (1.f + expf(-(pp + b3v)));
  }
}

extern "C" void kernel_launch(void* const* d_in, const int* in_sizes, int n_in,
                              void* d_out, int out_size, void* d_ws, size_t ws_size,
                              hipStream_t stream) {
  const int* concepts = (const int*)d_in[0];
  const int* interactions = (const int*)d_in[1];
  const float* Kmem = (const float*)d_in[2];
  const float* Vmem = (const float*)d_in[3];
  const float* cemb = (const float*)d_in[4];
  const float* iemb = (const float*)d_in[5];
  const float* We = (const float*)d_in[6];
  const float* be = (const float*)d_in[7];
  const float* Wa = (const float*)d_in[8];
  const float* ba = (const float*)d_in[9];
  const float* W1 = (const float*)d_in[10];
  const float* b1 = (const float*)d_in[11];
  const float* W2 = (const float*)d_in[12];
  const float* b2 = (const float*)d_in[13];
  const float* W3 = (const float*)d_in[14];
  const float* b3 = (const float*)d_in[15];
  float* out = (float*)d_out;

  const size_t sz_w = (size_t)NCID * N_ * 4;
  const size_t sz_e = (size_t)NIID * DV_ * 4;
  float* wtab = (float*)d_ws;
  float* etab = (float*)((char*)d_ws + sz_w);
  float* atab = (float*)((char*)d_ws + sz_w + sz_e);
  h16* rpart = (h16*)((char*)d_ws + sz_w + 2 * sz_e);  // 2 x 64 MiB

  kW<<<dim3(NCID), dim3(512), 0, stream>>>(Kmem, cemb, wtab);
  kG<<<dim3((NIID + 7) / 8), dim3(512), 0, stream>>>(iemb, We, be, Wa, ba, etab, atab);
  kS<<<dim3(B_ * 2), dim3(1024), 0, stream>>>(concepts, interactions, Vmem,
                                              wtab, etab, atab, rpart);
  kM<<<dim3(NP_ / MP_), dim3(512), 0, stream>>>(concepts, cemb, rpart,
                                                W1, b1, W2, b2, W3, b3, out);
}

// Round 10
// 1446.238 us; speedup vs baseline: 19.2450x; 1.0860x over previous
//
#include <hip/hip_runtime.h>

// DKVMN forward, round 24 — RESUBMIT of round 23 (bench infra failed twice;
// no measurement was taken). Unchanged source, unchanged hypothesis:
// round-6 green kernel EXACTLY, single variable changed: kS EPSW 1e-7 -> 1e-6.
// R21/R22 both failed with BIT-IDENTICAL absmax 0.105 despite different kS
// kernels -> the shared component (kM's new u32x4/bit_cast/fdot2 layer-1 read
// path) is the deterministic culprit; fdot2 banned. Error budget for EPSW
// 1e-6: skipped weight mass <= 512e-6 = 5.1e-4 in r; worst-case cold-row m
// drift ~3e-3 -> absmax <= ~7e-3 < 1.078e-2 threshold.
//   kW: wtab[513][512] fp32   kG: etab/atab[1025][256] fp32   (3.2 MB, hot)
//   kS: 512 blocks x 1024 thr; 16-step tiles; s_racc[4][16][DV]; named
//       m0..m15; unroll-1 j-loop; tid<256 float4 unroll-4 drain; GRP4 skip.
//   kM: round-6-exact MLP head (s_f fp32, s_W1 fp16, dot4 fma).
// ws = 3.2 MB + 128 MiB.

#define B_ 256
#define T_ 512
#define N_ 512
#define DK_ 64
#define DV_ 256
#define S_ 64
#define NP_ (B_ * T_)
#define NCID 513
#define NIID 1025
#define TB_ 16
#define EPSW 1e-6f

typedef _Float16 h16;
typedef __attribute__((ext_vector_type(4))) _Float16 half4;

__device__ __forceinline__ float dot4(float4 a, float4 b) {
  return a.x * b.x + a.y * b.y + a.z * b.z + a.w * b.w;
}
__device__ __forceinline__ float4 h2f(half4 h) {
  return make_float4((float)h.x, (float)h.y, (float)h.z, (float)h.w);
}
__device__ __forceinline__ half4 f2h(float4 f) {
  half4 h;
  h.x = (h16)f.x; h.y = (h16)f.y; h.z = (h16)f.z; h.w = (h16)f.w;
  return h;
}

// ============ kW: wtab[c][n] = softmax_n(q_c . K_n), 513 blocks ============
__global__ __launch_bounds__(512) void kW(const float* __restrict__ Kmem,
                                          const float* __restrict__ cemb,
                                          float* __restrict__ wtab) {
  __shared__ float s_q[DK_];
  __shared__ float s_red[16];
  const int tid = threadIdx.x, c = blockIdx.x;
  if (tid < DK_) s_q[tid] = c ? cemb[c * DK_ + tid] : 0.f;
  __syncthreads();
  const int n = tid;
  const float4* kr = (const float4*)(Kmem + n * DK_);
  float acc = 0.f;
#pragma unroll
  for (int kk = 0; kk < DK_ / 4; ++kk) acc += dot4(kr[kk], *(const float4*)&s_q[kk * 4]);
  const int lane = tid & 63, wid = tid >> 6;
  float mx = acc;
  for (int off = 32; off; off >>= 1) mx = fmaxf(mx, __shfl_xor(mx, off, 64));
  if (lane == 0) s_red[wid] = mx;
  __syncthreads();
  float gmx = s_red[0];
#pragma unroll
  for (int i = 1; i < 8; ++i) gmx = fmaxf(gmx, s_red[i]);
  const float e = expf(acc - gmx);
  float sum = e;
  for (int off = 32; off; off >>= 1) sum += __shfl_xor(sum, off, 64);
  if (lane == 0) s_red[8 + wid] = sum;
  __syncthreads();
  float gs = 0.f;
#pragma unroll
  for (int i = 0; i < 8; ++i) gs += s_red[8 + i];
  wtab[c * N_ + n] = e / gs;
}

// ============ kG: etab/atab[id][d], 129 blocks x 8 ids =====================
__global__ __launch_bounds__(512) void kG(const float* __restrict__ iemb,
                                          const float* __restrict__ We,
                                          const float* __restrict__ be,
                                          const float* __restrict__ Wa,
                                          const float* __restrict__ ba,
                                          float* __restrict__ etab,
                                          float* __restrict__ atab) {
  __shared__ float s_v[8 * DV_];
  const int tid = threadIdx.x, bi = blockIdx.x;
  {
    const int j = tid >> 6, c4 = tid & 63;
    const int id = bi * 8 + j;
    float4 v = make_float4(0.f, 0.f, 0.f, 0.f);
    if (id >= 1 && id < NIID) v = ((const float4*)iemb)[(size_t)id * 64 + c4];
    *(float4*)&s_v[j * DV_ + c4 * 4] = v;
  }
  __syncthreads();
  const int gate = tid >> 8, d = tid & 255;
  const float4* wr = (const float4*)((gate ? Wa : We) + d * DV_);
  float acc[8];
#pragma unroll
  for (int j = 0; j < 8; ++j) acc[j] = 0.f;
  for (int kk = 0; kk < DV_ / 4; ++kk) {
    const float4 w4 = wr[kk];
#pragma unroll
    for (int j = 0; j < 8; ++j) acc[j] += dot4(w4, *(const float4*)&s_v[j * DV_ + kk * 4]);
  }
  const float bias = gate ? ba[d] : be[d];
#pragma unroll
  for (int j = 0; j < 8; ++j) {
    const int id = bi * 8 + j;
    if (id < NIID) {
      if (gate) atab[(size_t)id * DV_ + d] = tanhf(acc[j] + bias);
      else      etab[(size_t)id * DV_ + d] = 1.f / (1.f + expf(-(acc[j] + bias)));
    }
  }
}

// ============ kS: sparse DS+VALU recurrence, 512 blocks x 1024 thr =========
// Round-6-exact except EPSW. block = (b, ch); wave owns 16 rows as NAMED
// float4 registers; anti-spill invariants: unroll-1 j-loop, tid<256 float4
// unroll-4 drain.
#define ROWOP(mr, wsel)                                   \
  do {                                                    \
    const float w_ = (wsel);                              \
    racc.x = fmaf(w_, mr.x, racc.x);                      \
    racc.y = fmaf(w_, mr.y, racc.y);                      \
    racc.z = fmaf(w_, mr.z, racc.z);                      \
    racc.w = fmaf(w_, mr.w, racc.w);                      \
    mr.x = fmaf(-w_, fmaf(e4.x, mr.x, -a4.x), mr.x);      \
    mr.y = fmaf(-w_, fmaf(e4.y, mr.y, -a4.y), mr.y);      \
    mr.z = fmaf(-w_, fmaf(e4.z, mr.z, -a4.z), mr.z);      \
    mr.w = fmaf(-w_, fmaf(e4.w, mr.w, -a4.w), mr.w);      \
  } while (0)

#define GRP4(wq, A, B, C, D)                                              \
  do {                                                                    \
    const float gmx_ = fmaxf(fmaxf(wq.x, wq.y), fmaxf(wq.z, wq.w));       \
    if (__int_as_float(__builtin_amdgcn_readfirstlane(                    \
            __float_as_int(gmx_))) > EPSW) {                              \
      ROWOP(A, wq.x); ROWOP(B, wq.y); ROWOP(C, wq.z); ROWOP(D, wq.w);     \
    }                                                                     \
  } while (0)

__global__ __launch_bounds__(1024)
__attribute__((amdgpu_waves_per_eu(4, 4))) void kS(
    const int* __restrict__ concepts, const int* __restrict__ inter,
    const float* __restrict__ Vmem, const float* __restrict__ wtab,
    const float* __restrict__ etab, const float* __restrict__ atab,
    h16* __restrict__ rpart) {
  __shared__ float s_w[TB_][DV_];        // 16 KB: w[t][block's 256-row chunk]
  __shared__ float s_e[TB_][DV_];        // 16 KB
  __shared__ float s_a[TB_][DV_];        // 16 KB
  __shared__ float s_racc[4][16][DV_];   // 64 KB: 4 steps x 16 wave-partials
  const int tid = threadIdx.x, bx = blockIdx.x;
  const int b = bx >> 1, ch = bx & 1;
  const int lane = tid & 63, wv = tid >> 6;  // 16 waves
  const int row0 = ch * 256 + __builtin_amdgcn_readfirstlane(wv * 16);
  float4 m0, m1, m2, m3, m4, m5, m6, m7, m8, m9, m10, m11, m12, m13, m14, m15;
  {
    const float4* vm4 = (const float4*)Vmem + (size_t)row0 * 64 + lane;
    m0 = vm4[0 * 64];   m1 = vm4[1 * 64];   m2 = vm4[2 * 64];   m3 = vm4[3 * 64];
    m4 = vm4[4 * 64];   m5 = vm4[5 * 64];   m6 = vm4[6 * 64];   m7 = vm4[7 * 64];
    m8 = vm4[8 * 64];   m9 = vm4[9 * 64];   m10 = vm4[10 * 64]; m11 = vm4[11 * 64];
    m12 = vm4[12 * 64]; m13 = vm4[13 * 64]; m14 = vm4[14 * 64]; m15 = vm4[15 * 64];
  }
  const int* cb = concepts + b * T_;
  const int* ib = inter + b * T_;
  const float4* wtab4 = (const float4*)wtab;
  const float4* etab4 = (const float4*)etab;
  const float4* atab4 = (const float4*)atab;
  h16* rp = rpart + (size_t)ch * NP_ * DV_ + (size_t)b * T_ * DV_;

  // cooperative tile staging: w/e/a rows for 16 steps (3 float4 loads/thread,
  // tables are L2-resident).
  auto stage = [&](int t0) {
    const int tl = tid >> 6, c4 = tid & 63;
    const int cv = cb[t0 + tl];
    const int iv = ib[t0 + tl];
    *(float4*)&s_w[tl][c4 * 4] = wtab4[(size_t)cv * 128 + ch * 64 + c4];
    *(float4*)&s_e[tl][c4 * 4] = etab4[(size_t)iv * 64 + c4];
    *(float4*)&s_a[tl][c4 * 4] = atab4[(size_t)iv * 64 + c4];
  };

  stage(0);
  __syncthreads();

  for (int t0 = 0; t0 < T_; t0 += TB_) {
    for (int s = 0; s < 4; ++s) {  // 4 sub-tiles of 4 steps
#pragma unroll 1                   // CAP PRESSURE: one step's LDS reads live
      for (int j = 0; j < 4; ++j) {
        const int tl = s * 4 + j;
        // wave-uniform broadcast reads: this wave's 16 w values
        const float* wrow = &s_w[tl][wv * 16];
        const float4 wq0 = *(const float4*)(wrow + 0);
        const float4 wq1 = *(const float4*)(wrow + 4);
        const float4 wq2 = *(const float4*)(wrow + 8);
        const float4 wq3 = *(const float4*)(wrow + 12);
        const float4 e4 = *(const float4*)&s_e[tl][lane * 4];
        const float4 a4 = *(const float4*)&s_a[tl][lane * 4];
        float4 racc = make_float4(0.f, 0.f, 0.f, 0.f);
        GRP4(wq0, m0, m1, m2, m3);
        GRP4(wq1, m4, m5, m6, m7);
        GRP4(wq2, m8, m9, m10, m11);
        GRP4(wq3, m12, m13, m14, m15);
        // plain per-wave partial write — no atomics
        *(float4*)&s_racc[j][wv][lane * 4] = racc;
      }
      __syncthreads();
      // overlap next-tile staging with the drain (independent LDS regions)
      if (s == 3 && t0 + TB_ < T_) stage(t0 + TB_);
      if (tid < 256) {
        // drain: 4 waves reduce 16 wave-partials; unroll 4 bounds live temps.
        const int j = tid >> 6, l = tid & 63;
        float4 acc = make_float4(0.f, 0.f, 0.f, 0.f);
#pragma unroll 4
        for (int w2 = 0; w2 < 16; ++w2) {
          const float4 v = *(const float4*)&s_racc[j][w2][l * 4];
          acc.x += v.x; acc.y += v.y; acc.z += v.z; acc.w += v.w;
        }
        *(half4*)(rp + (size_t)(t0 + s * 4 + j) * DV_ + l * 4) = f2h(acc);
      }
      __syncthreads();
    }
  }
}

// ============ kM: MLP head, 2048 blocks x 512 thr (round-6-exact) ==========
#define MP_ 64
__global__ __launch_bounds__(512) void kM(const int* __restrict__ concepts,
                                          const float* __restrict__ cemb,
                                          const h16* __restrict__ rpart,
                                          const float* __restrict__ W1,
                                          const float* __restrict__ b1,
                                          const float* __restrict__ W2,
                                          const float* __restrict__ b2,
                                          const float* __restrict__ W3,
                                          const float* __restrict__ b3,
                                          float* __restrict__ out) {
  __shared__ float s_f[MP_][DV_ + DK_];  // 80 KB
  __shared__ h16 s_W1[S_][324];          // 40.5 KB (padded)
  __shared__ float s_h1[8][8][S_];       // 16 KB
  __shared__ int s_c[MP_];
  const int tid = threadIdx.x, g = blockIdx.x;
  const int lane = tid & 63, wv = tid >> 6;
  if (tid < MP_) s_c[tid] = concepts[g * MP_ + tid];
  {
    const int j = tid >> 3, f0 = tid & 7;
    const float4* w1r = (const float4*)(W1 + j * 320);
#pragma unroll
    for (int i = 0; i < 10; ++i) {
      const int k4 = f0 + i * 8;
      *(half4*)&s_W1[j][k4 * 4] = f2h(w1r[k4]);
    }
  }
  __syncthreads();
  {
    const half4* p0 = (const half4*)rpart;
    const half4* p1 = p0 + (size_t)NP_ * 64;
#pragma unroll
    for (int i = 0; i < 8; ++i) {
      const int idx = tid + i * 512, p = idx >> 6, c4 = idx & 63;
      const size_t off = (size_t)(g * MP_ + p) * 64 + c4;
      const float4 v0 = h2f(p0[off]);
      const float4 v1 = h2f(p1[off]);
      *(float4*)&s_f[p][c4 * 4] =
          make_float4(v0.x + v1.x, v0.y + v1.y, v0.z + v1.z, v0.w + v1.w);
    }
    const float4* ce4 = (const float4*)cemb;
    const float4 z = make_float4(0.f, 0.f, 0.f, 0.f);
#pragma unroll
    for (int i = 0; i < 2; ++i) {
      const int idx = tid + i * 512, p = idx >> 4, k4 = idx & 15;
      const int c = s_c[p];
      *(float4*)&s_f[p][DV_ + k4 * 4] = c ? ce4[c * 16 + k4] : z;
    }
  }
  __syncthreads();
  const int j = lane;
  float acc[8];
  {
    const float b1j = b1[j];
#pragma unroll
    for (int p = 0; p < 8; ++p) acc[p] = b1j;
  }
  for (int k4 = 0; k4 < 80; ++k4) {
    const float4 w4 = h2f(*(const half4*)&s_W1[j][k4 * 4]);
#pragma unroll
    for (int p = 0; p < 8; ++p)
      acc[p] += dot4(w4, *(const float4*)&s_f[wv * 8 + p][k4 * 4]);
  }
#pragma unroll
  for (int p = 0; p < 8; ++p) s_h1[wv][p][j] = fmaxf(acc[p], 0.f);
  __syncthreads();
  {
    const float b2j = b2[j];
#pragma unroll
    for (int p = 0; p < 8; ++p) acc[p] = b2j;
  }
  const float4* w2r = (const float4*)(W2 + j * S_);
#pragma unroll
  for (int k4 = 0; k4 < S_ / 4; ++k4) {
    const float4 w4 = w2r[k4];
#pragma unroll
    for (int p = 0; p < 8; ++p)
      acc[p] += dot4(w4, *(const float4*)&s_h1[wv][p][k4 * 4]);
  }
  const float w3j = W3[j], b3v = b3[0];
#pragma unroll
  for (int p = 0; p < 8; ++p) {
    float pp = fmaxf(acc[p], 0.f) * w3j;
    for (int off = 32; off; off >>= 1) pp += __shfl_xor(pp, off, 64);
    if (lane == 0)
      out[g * MP_ + wv * 8 + p] = 1.f / (1.f + expf(-(pp + b3v)));
  }
}

extern "C" void kernel_launch(void* const* d_in, const int* in_sizes, int n_in,
                              void* d_out, int out_size, void* d_ws, size_t ws_size,
                              hipStream_t stream) {
  const int* concepts = (const int*)d_in[0];
  const int* interactions = (const int*)d_in[1];
  const float* Kmem = (const float*)d_in[2];
  const float* Vmem = (const float*)d_in[3];
  const float* cemb = (const float*)d_in[4];
  const float* iemb = (const float*)d_in[5];
  const float* We = (const float*)d_in[6];
  const float* be = (const float*)d_in[7];
  const float* Wa = (const float*)d_in[8];
  const float* ba = (const float*)d_in[9];
  const float* W1 = (const float*)d_in[10];
  const float* b1 = (const float*)d_in[11];
  const float* W2 = (const float*)d_in[12];
  const float* b2 = (const float*)d_in[13];
  const float* W3 = (const float*)d_in[14];
  const float* b3 = (const float*)d_in[15];
  float* out = (float*)d_out;

  const size_t sz_w = (size_t)NCID * N_ * 4;
  const size_t sz_e = (size_t)NIID * DV_ * 4;
  float* wtab = (float*)d_ws;
  float* etab = (float*)((char*)d_ws + sz_w);
  float* atab = (float*)((char*)d_ws + sz_w + sz_e);
  h16* rpart = (h16*)((char*)d_ws + sz_w + 2 * sz_e);  // 2 x 64 MiB

  kW<<<dim3(NCID), dim3(512), 0, stream>>>(Kmem, cemb, wtab);
  kG<<<dim3((NIID + 7) / 8), dim3(512), 0, stream>>>(iemb, We, be, Wa, ba, etab, atab);
  kS<<<dim3(B_ * 2), dim3(1024), 0, stream>>>(concepts, interactions, Vmem,
                                              wtab, etab, atab, rpart);
  kM<<<dim3(NP_ / MP_), dim3(512), 0, stream>>>(concepts, cemb, rpart,
                                                W1, b1, W2, b2, W3, b3, out);
}